// Round 18
// baseline (511.656 us; speedup 1.0000x reference)
//
#include <hip/hip_runtime.h>

typedef _Float16 f16;
typedef f16 f16x4 __attribute__((ext_vector_type(4)));
typedef f16 f16x8 __attribute__((ext_vector_type(8)));
typedef float f32x4 __attribute__((ext_vector_type(4)));

// async global->LDS, 16B per lane; lds ptr must be wave-uniform base (HW adds lane*16)
__device__ __forceinline__ void gload16(const void* g, void* ldsbase) {
  __builtin_amdgcn_global_load_lds((const __attribute__((address_space(1))) unsigned int*)g,
                                   (__attribute__((address_space(3))) unsigned int*)ldsbase, 16, 0, 0);
}

// swizzled byte offset of 16B chunk c (k-chunk) of row `row` in a [rows][32] f16 tile (BK=32 kernels)
__device__ __forceinline__ int swz(int row, int c) {
  return row * 64 + ((c ^ ((row >> 1) & 3)) << 4);
}

// ================= 256x256 tile, BK=64, 512 threads, counted-vmcnt schedule =================
// MODE 2: E = exp(A*B^T * scale) -> E16 [M x N] + E16t [N x M] + col partial sums (aux)
template<int MODE>
__global__ void __launch_bounds__(512, 2)
gemm256(const f16* __restrict__ A, const f16* __restrict__ Bm, float* __restrict__ Cf,
        f16* __restrict__ E16, f16* __restrict__ E16t,
        int K, long sA, long sB, float scale, float* __restrict__ aux) {
  __shared__ f16 sb[65536];  // 128 KB: A0[16384] B0[16384] A1[16384] B1[16384]
  const int t = threadIdx.x, l = t & 63, w = t >> 6;
  const int wr = w >> 2, wc = w & 3;
  const int bid = blockIdx.x;
  const int swzb = (bid & 7) * 64 + (bid >> 3);  // XCD-chunked (512 % 8 == 0)
  const long b = swzb >> 6;
  const int inner = swzb & 63;
  const int bx = inner >> 2, by = inner & 3;  // by fastest: 4 consecutive blocks share B-panel in L2
  const char* Abyte = (const char*)(A + b * sA + (long)(by * 256) * K);
  const char* Bbyte = (const char*)(Bm + b * sB + (long)(bx * 256) * K);

  int offSrc[4];
#pragma unroll
  for (int i = 0; i < 4; ++i) {
    int cid = i * 512 + t, row = cid >> 3, slot = cid & 7;
    offSrc[i] = row * (K * 2) + ((slot ^ (row & 7)) << 4);
  }
  int offAf[8][2], offBf[4][2];
#pragma unroll
  for (int mi = 0; mi < 8; ++mi) {
    int r = wr * 128 + mi * 16 + (l & 15);
#pragma unroll
    for (int ks = 0; ks < 2; ++ks)
      offAf[mi][ks] = r * 64 + ((((ks << 2) + (l >> 4)) ^ (r & 7)) << 3);
  }
#pragma unroll
  for (int ni = 0; ni < 4; ++ni) {
    int r = wc * 64 + ni * 16 + (l & 15);
#pragma unroll
    for (int ks = 0; ks < 2; ++ks)
      offBf[ni][ks] = r * 64 + ((((ks << 2) + (l >> 4)) ^ (r & 7)) << 3);
  }

  const int NT = K >> 6;
  f32x4 acc[8][4] = {};

  auto STAGE = [&](int kt, int bsel) {
    f16* la = sb + bsel * 32768;
    f16* lb = la + 16384;
    const char* as = Abyte + (long)kt * 128;
    const char* bs = Bbyte + (long)kt * 128;
#pragma unroll
    for (int i = 0; i < 4; ++i)
      gload16(as + offSrc[i], la + (i * 512 + (w << 6)) * 8);
#pragma unroll
    for (int i = 0; i < 4; ++i)
      gload16(bs + offSrc[i], lb + (i * 512 + (w << 6)) * 8);
  };

  STAGE(0, 0);
  for (int kt = 0; kt < NT; ++kt) {
    const int cur = kt & 1;
    if (kt + 1 < NT) {
      STAGE(kt + 1, cur ^ 1);
      asm volatile("s_waitcnt vmcnt(8)" ::: "memory");
    } else {
      asm volatile("s_waitcnt vmcnt(0)" ::: "memory");
    }
    __builtin_amdgcn_s_barrier();
    asm volatile("" ::: "memory");
    const f16* la = sb + cur * 32768;
    const f16* lb = la + 16384;
#pragma unroll
    for (int ks = 0; ks < 2; ++ks) {
      f16x8 bf[4];
#pragma unroll
      for (int ni = 0; ni < 4; ++ni) bf[ni] = *(const f16x8*)(lb + offBf[ni][ks]);
#pragma unroll
      for (int mi = 0; mi < 8; ++mi) {
        f16x8 af = *(const f16x8*)(la + offAf[mi][ks]);
#pragma unroll
        for (int ni = 0; ni < 4; ++ni)
          acc[mi][ni] = __builtin_amdgcn_mfma_f32_16x16x32_f16(af, bf[ni], acc[mi][ni], 0, 0, 0);
      }
    }
    asm volatile("s_waitcnt lgkmcnt(0)" ::: "memory");
    __builtin_amdgcn_s_barrier();
    asm volatile("" ::: "memory");
  }

  const int i0 = by * 256, j0 = bx * 256;
  if (MODE == 2) {
    float csum[4] = {};
#pragma unroll
    for (int mi = 0; mi < 8; ++mi)
#pragma unroll
      for (int ni = 0; ni < 4; ++ni)
#pragma unroll
        for (int q = 0; q < 4; ++q) {
          float e = __expf(acc[mi][ni][q] * scale);
          acc[mi][ni][q] = e;
          csum[ni] += e;
        }
#pragma unroll
    for (int ni = 0; ni < 4; ++ni) {
      csum[ni] += __shfl_xor(csum[ni], 16);
      csum[ni] += __shfl_xor(csum[ni], 32);
    }
    float* colp = (float*)(sb + 34816);
    if (l < 16) {
#pragma unroll
      for (int ni = 0; ni < 4; ++ni) colp[wr * 256 + wc * 64 + ni * 16 + l] = csum[ni];
    }
    __syncthreads();
    if (t < 256) aux[(b * 4 + by) * 4096 + bx * 256 + t] = colp[t] + colp[256 + t];
    f16* E16b = E16 + b * 4194304L;
    f16* E16tb = E16t + b * 4194304L;
#pragma unroll
    for (int s = 0; s < 4; ++s) {
      if (wr == (s >> 1)) {
        const int h = s & 1;
#pragma unroll
        for (int m2 = 0; m2 < 4; ++m2)
#pragma unroll
          for (int ni = 0; ni < 4; ++ni)
#pragma unroll
            for (int q = 0; q < 4; ++q)
              sb[(m2 * 16 + (l >> 4) * 4 + q) * 264 + wc * 64 + ni * 16 + (l & 15)] =
                  (f16)acc[h * 4 + m2][ni][q];
      }
      __syncthreads();
#pragma unroll
      for (int ii = 0; ii < 4; ++ii) {
        int cid = ii * 512 + t, r = cid >> 5, cc = cid & 31;
        *(f16x8*)(E16b + (long)(i0 + s * 64 + r) * 4096 + j0 + cc * 8) =
            *(const f16x8*)(sb + r * 264 + cc * 8);
      }
      const int q4 = w >> 1, r8 = l >> 3, ic = l & 7;
#pragma unroll
      for (int ii = 0; ii < 4; ++ii) {
        int j = q4 * 64 + r8 * 8 + (w & 1) * 4 + ii;
        f16x8 v;
#pragma unroll
        for (int k2 = 0; k2 < 8; ++k2) v[k2] = sb[(ic * 8 + k2) * 264 + j];
        *(f16x8*)(E16tb + (long)(j0 + j) * 1024 + i0 + s * 64 + ic * 8) = v;
      }
      __syncthreads();
    }
  }
}

// ================= fused: split-K gram (160) + MODE3 (512) + gram-reduce (80) = 752 blocks ====
// bids 0..159: gram half-K block -> midS partial; publish via threadfence+ctrG.
// bids 160..671: out = (Q * E^T) * inv[col]  (verified gemm256<3> body, K=1024)
// bids 672..751: wait ctrG==160, then reduce tile (bid-672): sum halves, -I, square -> parts;
//   last reducer (ctrR==79) sums 80 parts -> *loss_out.
__global__ void __launch_bounds__(512, 2)
fused3(const f16* __restrict__ Q, const f16* __restrict__ Et, float* __restrict__ Cf,
       const float* __restrict__ invg,
       const f16* __restrict__ E, const f16* __restrict__ inv2sg,
       float* __restrict__ Hf, float* __restrict__ midS,
       float* __restrict__ parts, int* __restrict__ ctrG, int* __restrict__ ctrR,
       float* __restrict__ loss_out) {
  __shared__ f16 sb[69632];  // 136 KB (gram uses all; MODE3 uses first 128 KB)
  const int t = threadIdx.x, l = t & 63, w = t >> 6;
  const int wr = w >> 2, wc = w & 3;

  if (blockIdx.x < 160) {  // ---------------- gram half-K path
    const int bid = blockIdx.x;
    const long b = bid & 7;            // batch = XCD
    const int rest = bid >> 3;         // 0..19
    const int h = rest & 1;            // K-half
    int by = 0, r = rest >> 1;         // triangular 0..9 -> (by, bx), bx >= by
    while (r >= 4 - by) { r -= 4 - by; ++by; }
    const int bx = by + r;
    const char* Abyte = (const char*)(E + b * 4194304L + (long)(by * 256) * 4096 + 2048L * h);
    const char* Bbyte = (const char*)(E + b * 4194304L + (long)(bx * 256) * 4096 + 2048L * h);
    const int d = bx - by;
    const int wA = (d == 1) ? 0 : (d == 2 ? 1 : -1);
    const int wB = (d == 3) ? 0 : ((d == 1 && by >= 1) ? 1 : -1);
    f16* invl = sb + 65536;
    gload16((const char*)(inv2sg + b * 4096) + (long)t * 16, invl + (w << 6) * 8);
    int offSrc[4];
#pragma unroll
    for (int i = 0; i < 4; ++i) {
      int cid = i * 512 + t, row = cid >> 3, slot = cid & 7;
      offSrc[i] = row * 8192 + ((slot ^ (row & 7)) << 4);
    }
    int offAf[8][2], offBf[4][2];
#pragma unroll
    for (int mi = 0; mi < 8; ++mi) {
      int rr = wr * 128 + mi * 16 + (l & 15);
#pragma unroll
      for (int ks = 0; ks < 2; ++ks)
        offAf[mi][ks] = rr * 64 + ((((ks << 2) + (l >> 4)) ^ (rr & 7)) << 3);
    }
#pragma unroll
    for (int ni = 0; ni < 4; ++ni) {
      int rr = wc * 64 + ni * 16 + (l & 15);
#pragma unroll
      for (int ks = 0; ks < 2; ++ks)
        offBf[ni][ks] = rr * 64 + ((((ks << 2) + (l >> 4)) ^ (rr & 7)) << 3);
    }
    f32x4 acc[8][4] = {};
    auto STAGE = [&](int lk, int bsel) {
      f16* la = sb + bsel * 32768;
      f16* lb = la + 16384;
      const char* as = Abyte + (long)lk * 128;
      const char* bs = Bbyte + (long)lk * 128;
#pragma unroll
      for (int i = 0; i < 4; ++i) gload16(as + offSrc[i], la + (i * 512 + (w << 6)) * 8);
#pragma unroll
      for (int i = 0; i < 4; ++i) gload16(bs + offSrc[i], lb + (i * 512 + (w << 6)) * 8);
    };
    STAGE(0, 0);
    for (int lk = 0; lk < 32; ++lk) {
      const int cur = lk & 1;
      if (lk + 1 < 32) {
        STAGE(lk + 1, cur ^ 1);
        const int ps = (lk - 1) >> 4;
        const bool wrote = (lk >= 1) && (wA == ps || wB == ps);
        if (wrote) asm volatile("s_waitcnt vmcnt(40)" ::: "memory");
        else       asm volatile("s_waitcnt vmcnt(8)" ::: "memory");
      } else {
        asm volatile("s_waitcnt vmcnt(0)" ::: "memory");
      }
      __builtin_amdgcn_s_barrier();
      asm volatile("" ::: "memory");
      const int ktg = 32 * h + lk;  // global K-tile index (64 cols each)
      const f16* la = sb + cur * 32768;
      const f16* lb = la + 16384;
#pragma unroll
      for (int ks = 0; ks < 2; ++ks) {
        const f16x8 invv = *(const f16x8*)(invl + ktg * 64 + ks * 32 + ((l >> 4) << 3));
        f16x8 bf[4];
#pragma unroll
        for (int ni = 0; ni < 4; ++ni) bf[ni] = *(const f16x8*)(lb + offBf[ni][ks]);
#pragma unroll
        for (int mi = 0; mi < 8; ++mi) {
          f16x8 af = *(const f16x8*)(la + offAf[mi][ks]) * invv;  // A-side only: inv^2*4096
#pragma unroll
          for (int ni = 0; ni < 4; ++ni)
            acc[mi][ni] = __builtin_amdgcn_mfma_f32_16x16x32_f16(af, bf[ni], acc[mi][ni], 0, 0, 0);
        }
      }
      const int slot = lk >> 4;
      if (wA == slot || wB == slot) {  // fused Hf writer (at most one per iteration)
        const int panel = (wA == slot) ? by : bx;
        const f16* src = (wA == slot) ? la : lb;
        const float iv = sqrtf((float)invl[ktg * 64 + l]) * (1.0f / 64.0f);  // inv = sqrt(inv2s)/64
        float* hp = Hf + b * 4194304L + (long)(panel * 256 + w * 32) * 4096 + ktg * 64 + l;
#pragma unroll
        for (int rr2 = 0; rr2 < 32; ++rr2) {
          const int row = w * 32 + rr2;  // 8 waves x 32 rows
          f16 ev = src[row * 64 + ((((l >> 3) ^ (row & 7)) << 3) | (l & 7))];
          hp[(long)rr2 * 4096] = (float)ev * iv;
        }
      }
      asm volatile("s_waitcnt lgkmcnt(0)" ::: "memory");
      __builtin_amdgcn_s_barrier();
      asm volatile("" ::: "memory");
    }
    // store partial mid tile (f32) to scratch, then publish
    float* mt = midS + (long)(((rest >> 1) * 8 + b) * 2 + h) * 65536;
#pragma unroll
    for (int mi = 0; mi < 8; ++mi)
#pragma unroll
      for (int ni = 0; ni < 4; ++ni)
#pragma unroll
        for (int q = 0; q < 4; ++q)
          mt[(wr * 128 + mi * 16 + (l >> 4) * 4 + q) * 256 + wc * 64 + ni * 16 + (l & 15)] =
              acc[mi][ni][q];
    __threadfence();
    __syncthreads();
    if (t == 0) atomicAdd(ctrG, 1);
  } else if (blockIdx.x < 672) {  // ---------------- MODE3 path (verified gemm256<3> body)
    const int bid = blockIdx.x - 160;
    const int swzb = (bid & 7) * 64 + (bid >> 3);
    const long b = swzb >> 6;
    const int inner = swzb & 63;
    const int bx = inner >> 2, by = inner & 3;
    const char* Abyte = (const char*)(Q + b * 1048576L + (long)(by * 256) * 1024);
    const char* Bbyte = (const char*)(Et + b * 4194304L + (long)(bx * 256) * 1024);
    int offSrc[4];
#pragma unroll
    for (int i = 0; i < 4; ++i) {
      int cid = i * 512 + t, row = cid >> 3, slot = cid & 7;
      offSrc[i] = row * 2048 + ((slot ^ (row & 7)) << 4);
    }
    int offAf[8][2], offBf[4][2];
#pragma unroll
    for (int mi = 0; mi < 8; ++mi) {
      int r = wr * 128 + mi * 16 + (l & 15);
#pragma unroll
      for (int ks = 0; ks < 2; ++ks)
        offAf[mi][ks] = r * 64 + ((((ks << 2) + (l >> 4)) ^ (r & 7)) << 3);
    }
#pragma unroll
    for (int ni = 0; ni < 4; ++ni) {
      int r = wc * 64 + ni * 16 + (l & 15);
#pragma unroll
      for (int ks = 0; ks < 2; ++ks)
        offBf[ni][ks] = r * 64 + ((((ks << 2) + (l >> 4)) ^ (r & 7)) << 3);
    }
    f32x4 acc[8][4] = {};
    auto STAGE = [&](int kt, int bsel) {
      f16* la = sb + bsel * 32768;
      f16* lb = la + 16384;
      const char* as = Abyte + (long)kt * 128;
      const char* bs = Bbyte + (long)kt * 128;
#pragma unroll
      for (int i = 0; i < 4; ++i) gload16(as + offSrc[i], la + (i * 512 + (w << 6)) * 8);
#pragma unroll
      for (int i = 0; i < 4; ++i) gload16(bs + offSrc[i], lb + (i * 512 + (w << 6)) * 8);
    };
    STAGE(0, 0);
    for (int kt = 0; kt < 16; ++kt) {
      const int cur = kt & 1;
      if (kt + 1 < 16) {
        STAGE(kt + 1, cur ^ 1);
        asm volatile("s_waitcnt vmcnt(8)" ::: "memory");
      } else {
        asm volatile("s_waitcnt vmcnt(0)" ::: "memory");
      }
      __builtin_amdgcn_s_barrier();
      asm volatile("" ::: "memory");
      const f16* la = sb + cur * 32768;
      const f16* lb = la + 16384;
#pragma unroll
      for (int ks = 0; ks < 2; ++ks) {
        f16x8 bf[4];
#pragma unroll
        for (int ni = 0; ni < 4; ++ni) bf[ni] = *(const f16x8*)(lb + offBf[ni][ks]);
#pragma unroll
        for (int mi = 0; mi < 8; ++mi) {
          f16x8 af = *(const f16x8*)(la + offAf[mi][ks]);
#pragma unroll
          for (int ni = 0; ni < 4; ++ni)
            acc[mi][ni] = __builtin_amdgcn_mfma_f32_16x16x32_f16(af, bf[ni], acc[mi][ni], 0, 0, 0);
        }
      }
      asm volatile("s_waitcnt lgkmcnt(0)" ::: "memory");
      __builtin_amdgcn_s_barrier();
      asm volatile("" ::: "memory");
    }
    const float* ip = invg + b * 4096 + bx * 256 + wc * 64;
    float iv[4];
#pragma unroll
    for (int ni = 0; ni < 4; ++ni) iv[ni] = ip[ni * 16 + (l & 15)];
    float* Cb = Cf + b * 4194304L + (long)(by * 256 + wr * 128) * 4096 + bx * 256 + wc * 64;
#pragma unroll
    for (int mi = 0; mi < 8; ++mi)
#pragma unroll
      for (int ni = 0; ni < 4; ++ni)
#pragma unroll
        for (int q = 0; q < 4; ++q)
          Cb[(long)(mi * 16 + (l >> 4) * 4 + q) * 4096 + ni * 16 + (l & 15)] = acc[mi][ni][q] * iv[ni];
  } else {  // ---------------- gram reduce path (80 blocks): gated on ctrG
    const int tile = blockIdx.x - 672;  // pairIdx*8 + b
    if (t == 0) {
      while (atomicAdd(ctrG, 0) < 160) __builtin_amdgcn_s_sleep(16);
    }
    __syncthreads();
    __threadfence();
    int by = 0, r = tile >> 3;
    while (r >= 4 - by) { r -= 4 - by; ++by; }
    const int bx = by + r;
    const bool diag = (by == bx);
    const float* m0 = midS + (long)(tile * 2) * 65536;
    const float* m1 = m0 + 65536;
    float p = 0.f;
    for (int i = t; i < 65536; i += 512) {
      float e = (m0[i] + m1[i]) * (1.0f / 4096.0f);
      if (diag && (i >> 8) == (i & 255)) e -= 1.f;
      p += e * e;
    }
    if (!diag) p *= 2.f;
#pragma unroll
    for (int d2 = 32; d2; d2 >>= 1) p += __shfl_down(p, d2);
    __shared__ float red[8];
    if (l == 0) red[w] = p;
    __syncthreads();
    if (t == 0) {
      float s = 0.f;
#pragma unroll
      for (int i = 0; i < 8; ++i) s += red[i];
      parts[tile] = s;
      __threadfence();
      int old = atomicAdd(ctrR, 1);
      if (old == 79) {  // last reducer: final sum
        __threadfence();
        float tot = 0.f;
        for (int i = 0; i < 80; ++i) tot += parts[i];
        *loss_out = tot * (1.0f / 8388608.0f);
      }
    }
  }
}

// ================= merged projections: one dispatch, 1280 blocks ==============================
__global__ void __launch_bounds__(512)
proj_all(const float* __restrict__ Xk, const float* __restrict__ Xq,
         const f16* __restrict__ Wq16, const f16* __restrict__ Wk16, const f16* __restrict__ Wv16,
         const float* __restrict__ bq, const float* __restrict__ bk, const float* __restrict__ bv,
         f16* __restrict__ Q, f16* __restrict__ Kt, f16* __restrict__ Vt) {
  __shared__ f16 sb[20480];
  const int t = threadIdx.x, l = t & 63, w = t >> 6;
  const int wrq = w >> 1, wcq = w & 1;

  if (blockIdx.x < 256) {  // Q+K path
    f16* Wqs = sb;
    f16* Wks = sb + 8192;
    f16* Xs = sb + 16384;
    const int bg = blockIdx.x >> 3, g = bg & 3;
    const long b = bg >> 2;
    const int p0 = (blockIdx.x & 7) * 128;
    const float* Xb = Xk + b * 1048576 + (long)g * 262144;
    const char* WqB = (const char*)(Wq16 + g * 65536);
    const char* WkB = (const char*)(Wk16 + g * 65536);
    int wOff[2];
#pragma unroll
    for (int i = 0; i < 2; ++i) {
      int c = i * 512 + t, row = c >> 2, slot = (c & 3) ^ ((row >> 1) & 3);
      wOff[i] = row * 512 + (slot << 4);
    }
    const int xp = t & 127, xc = t >> 7;
    const float* xS = Xb + (long)(xc * 8) * 1024 + p0 + xp;
    const int xo = swz(xp, xc);
    int offW[4], offX[4];
#pragma unroll
    for (int i = 0; i < 4; ++i) {
      int rc = wrq * 64 + i * 16 + (l & 15);
      offW[i] = swz(rc, l >> 4);
      int rp = wcq * 64 + i * 16 + (l & 15);
      offX[i] = swz(rp, l >> 4);
    }
    f32x4 accq[4][4] = {}, acck[4][4] = {};
    for (int k0 = 0; k0 < 256; k0 += 32) {
#pragma unroll
      for (int i = 0; i < 2; ++i) {
        gload16(WqB + wOff[i] + k0 * 2, Wqs + (i * 512 + (w << 6)) * 8);
        gload16(WkB + wOff[i] + k0 * 2, Wks + (i * 512 + (w << 6)) * 8);
      }
      const float* xs = xS + (long)k0 * 1024;
      f16x8 v;
#pragma unroll
      for (int d = 0; d < 8; ++d) v[d] = (f16)xs[(long)d * 1024];
      *(f16x8*)((char*)Xs + xo) = v;
      __syncthreads();
      f16x8 qf[4], kf[4], xf[4];
#pragma unroll
      for (int i = 0; i < 4; ++i) {
        qf[i] = *(const f16x8*)((const char*)Wqs + offW[i]);
        kf[i] = *(const f16x8*)((const char*)Wks + offW[i]);
        xf[i] = *(const f16x8*)((const char*)Xs + offX[i]);
      }
#pragma unroll
      for (int mi = 0; mi < 4; ++mi)
#pragma unroll
        for (int ni = 0; ni < 4; ++ni) {
          accq[mi][ni] = __builtin_amdgcn_mfma_f32_16x16x32_f16(qf[mi], xf[ni], accq[mi][ni], 0, 0, 0);
          acck[ni][mi] = __builtin_amdgcn_mfma_f32_16x16x32_f16(xf[ni], kf[mi], acck[ni][mi], 0, 0, 0);
        }
      __syncthreads();
    }
    f16* Qb = Q + b * 1048576 + (long)(g * 256 + wrq * 64) * 1024 + p0 + wcq * 64;
#pragma unroll
    for (int mi = 0; mi < 4; ++mi)
#pragma unroll
      for (int q = 0; q < 4; ++q) {
        float bv2 = bq[g * 256 + wrq * 64 + mi * 16 + (l >> 4) * 4 + q];
#pragma unroll
        for (int ni = 0; ni < 4; ++ni)
          Qb[(long)(mi * 16 + (l >> 4) * 4 + q) * 1024 + ni * 16 + (l & 15)] = (f16)(accq[mi][ni][q] + bv2);
      }
    f16* Kb = Kt + b * 1048576 + (long)(p0 + wcq * 64) * 1024 + g * 256 + wrq * 64;
    float bcol[4];
#pragma unroll
    for (int ni = 0; ni < 4; ++ni) bcol[ni] = bk[g * 256 + wrq * 64 + ni * 16 + (l & 15)];
#pragma unroll
    for (int mi = 0; mi < 4; ++mi)
#pragma unroll
      for (int q = 0; q < 4; ++q)
#pragma unroll
        for (int ni = 0; ni < 4; ++ni)
          Kb[(long)(mi * 16 + (l >> 4) * 4 + q) * 1024 + ni * 16 + (l & 15)] = (f16)(acck[mi][ni][q] + bcol[ni]);
  } else {  // V path
    f16* Wvs = sb;
    f16* Xs = sb + 8192;
    const int bid2 = blockIdx.x - 256;
    const int bg = bid2 >> 5, g = bg & 3;
    const long b = bg >> 2;
    const int p0 = (bid2 & 31) * 128;
    const float* Xb = Xq + b * 4194304 + (long)g * 1048576;
    const char* WvB = (const char*)(Wv16 + g * 65536);
    int wOff[2];
#pragma unroll
    for (int i = 0; i < 2; ++i) {
      int c = i * 512 + t, row = c >> 2, slot = (c & 3) ^ ((row >> 1) & 3);
      wOff[i] = row * 512 + (slot << 4);
    }
    const int xp = t & 127, xc = t >> 7;
    const float* xS = Xb + (long)(xc * 8) * 4096 + p0 + xp;
    const int xo = swz(xp, xc);
    int offW[4], offX[4];
#pragma unroll
    for (int i = 0; i < 4; ++i) {
      int rc = wrq * 64 + i * 16 + (l & 15);
      offW[i] = swz(rc, l >> 4);
      int rp = wcq * 64 + i * 16 + (l & 15);
      offX[i] = swz(rp, l >> 4);
    }
    f32x4 acc[4][4] = {};
    for (int k0 = 0; k0 < 256; k0 += 32) {
#pragma unroll
      for (int i = 0; i < 2; ++i)
        gload16(WvB + wOff[i] + k0 * 2, Wvs + (i * 512 + (w << 6)) * 8);
      const float* xs = xS + (long)k0 * 4096;
      f16x8 v;
#pragma unroll
      for (int d = 0; d < 8; ++d) v[d] = (f16)xs[(long)d * 4096];
      *(f16x8*)((char*)Xs + xo) = v;
      __syncthreads();
      f16x8 wf[4], xf[4];
#pragma unroll
      for (int i = 0; i < 4; ++i) {
        wf[i] = *(const f16x8*)((const char*)Wvs + offW[i]);
        xf[i] = *(const f16x8*)((const char*)Xs + offX[i]);
      }
#pragma unroll
      for (int mi = 0; mi < 4; ++mi)
#pragma unroll
        for (int ni = 0; ni < 4; ++ni)
          acc[mi][ni] = __builtin_amdgcn_mfma_f32_16x16x32_f16(xf[mi], wf[ni], acc[mi][ni], 0, 0, 0);
      __syncthreads();
    }
    f16* Vb = Vt + b * 4194304 + (long)(p0 + wcq * 64) * 1024 + g * 256 + wrq * 64;
    float bcol[4];
#pragma unroll
    for (int ni = 0; ni < 4; ++ni) bcol[ni] = bv[g * 256 + wrq * 64 + ni * 16 + (l & 15)];
#pragma unroll
    for (int mi = 0; mi < 4; ++mi)
#pragma unroll
      for (int q = 0; q < 4; ++q)
#pragma unroll
        for (int ni = 0; ni < 4; ++ni)
          Vb[(long)(mi * 16 + (l >> 4) * 4 + q) * 1024 + ni * 16 + (l & 15)] = (f16)(acc[mi][ni][q] + bcol[ni]);
  }
}

// ---------------- inv[b][j] = 1/colsum;  inv2s = inv^2*4096 (f16, for gram A-side scaling)
__global__ void __launch_bounds__(256)
inv_k(const float* __restrict__ colsum, float* __restrict__ inv, f16* __restrict__ inv2s) {
  int gid = blockIdx.x * 256 + threadIdx.x;  // 8*4096
  int b = gid >> 12, j = gid & 4095;
  const float* cp = colsum + (long)(b * 4) * 4096 + j;
  float s = 0.f;
#pragma unroll
  for (int my = 0; my < 4; ++my) s += cp[my * 4096];
  float iv = 1.f / s;
  inv[gid] = iv;
  inv2s[gid] = (f16)(iv * iv * 4096.0f);
}

// ---------------- fused f32->f16 weight convert + counter zeroing
__global__ void cvt3(const float* __restrict__ a, const float* __restrict__ b2,
                     const float* __restrict__ c, f16* __restrict__ da,
                     f16* __restrict__ db, f16* __restrict__ dc, int* __restrict__ ctrs) {
  int i = blockIdx.x * 256 + threadIdx.x;
  if (i < 2) ctrs[i] = 0;  // zero ctrG, ctrR each replay (graph-safe)
  int which = i >> 18, r = i & 262143;
  if (which == 0) da[r] = (f16)a[r];
  else if (which == 1) db[r] = (f16)b2[r];
  else dc[r] = (f16)c[r];
}

extern "C" void kernel_launch(void* const* d_in, const int* in_sizes, int n_in,
                              void* d_out, int out_size, void* d_ws, size_t ws_size,
                              hipStream_t stream) {
  const float* Xq = (const float*)d_in[0];
  const float* Xk = (const float*)d_in[1];
  const float* Wq = (const float*)d_in[2];
  const float* bq = (const float*)d_in[3];
  const float* Wk = (const float*)d_in[4];
  const float* bk = (const float*)d_in[5];
  const float* Wv = (const float*)d_in[6];
  const float* bv = (const float*)d_in[7];
  float* out = (float*)d_out;
  float* loss_out = out + 33554432;
  float* Hf = out + 33554433;  // H f32 output [8][1024][4096]

  char* ws = (char*)d_ws;
  f16* W16q = (f16*)(ws);
  f16* W16k = (f16*)(ws + (1 << 19));
  f16* W16v = (f16*)(ws + 2L * (1 << 19));
  f16* Q16  = (f16*)(ws + 3L * (1 << 19));                                  // [8][1024][1024]
  f16* Kt16 = (f16*)(ws + 3L * (1 << 19) + (1L << 24));                     // [8][1024][1024]
  f16* Vt16 = (f16*)(ws + 3L * (1 << 19) + 2L * (1 << 24));                 // [8][4096][1024]
  f16* E16  = (f16*)(ws + 3L * (1 << 19) + 2L * (1 << 24) + (1L << 26));    // [8][1024][4096]
  f16* E16t = (f16*)(ws + 3L * (1 << 19) + 2L * (1 << 24) + 2L * (1 << 26));// [8][4096][1024]
  char* tail = ws + 3L * (1 << 19) + 2L * (1 << 24) + 3L * (1 << 26);
  float* parts = (float*)tail;                         // 80 f32
  int*   ctrs  = (int*)(tail + 4096);                  // ctrG, ctrR
  float* invb  = (float*)(tail + 8192);                // [8][4096] f32
  f16*   inv2s = (f16*)(tail + 8192 + 131072);         // [8][4096] f16
  float* midS  = (float*)(tail + 8192 + 131072 + 65536); // 160 x 64K f32 = 40 MB
  // colsum [8][4][4096] f32 = 512KB, overlaps W16q (dead after projections)
  float* colsum = (float*)(ws);

  cvt3<<<3072, 256, 0, stream>>>(Wq, Wk, Wv, W16q, W16k, W16v, ctrs);

  // merged projections: Q natural + Kt + Vt in one dispatch (independent inputs Xk / Xq)
  proj_all<<<1280, 512, 0, stream>>>(Xk, Xq, W16q, W16k, W16v, bq, bk, bv, Q16, Kt16, Vt16);

  // E = exp(K^T V /32) -> E16 + E16t (f16) + column partial sums (256^2 tile, counted vmcnt)
  gemm256<2><<<512, 512, 0, stream>>>(Kt16, Vt16, nullptr, E16, E16t,
      1024, 1L << 20, 1L << 22, 0.03125f, colsum);

  inv_k<<<128, 256, 0, stream>>>(colsum, invb, inv2s);

  // fused: split-K gram + out-GEMM + counter-gated gram reduce & loss (one dispatch)
  fused3<<<752, 512, 0, stream>>>(Q16, E16t, out, invb, E16, inv2s, Hf, midS,
                                  parts, ctrs, ctrs + 1, loss_out);
}

// Round 19
// 370.845 us; speedup vs baseline: 1.3797x; 1.3797x over previous
//
#include <hip/hip_runtime.h>

typedef _Float16 f16;
typedef f16 f16x4 __attribute__((ext_vector_type(4)));
typedef f16 f16x8 __attribute__((ext_vector_type(8)));
typedef float f32x4 __attribute__((ext_vector_type(4)));

// async global->LDS, 16B per lane; lds ptr must be wave-uniform base (HW adds lane*16)
__device__ __forceinline__ void gload16(const void* g, void* ldsbase) {
  __builtin_amdgcn_global_load_lds((const __attribute__((address_space(1))) unsigned int*)g,
                                   (__attribute__((address_space(3))) unsigned int*)ldsbase, 16, 0, 0);
}

// swizzled byte offset of 16B chunk c (k-chunk) of row `row` in a [rows][32] f16 tile (BK=32 kernels)
__device__ __forceinline__ int swz(int row, int c) {
  return row * 64 + ((c ^ ((row >> 1) & 3)) << 4);
}

// ================= 256x256 tile, BK=64, 512 threads, counted-vmcnt schedule =================
// MODE 2: E = exp(A*B^T * scale) -> E16 [M x N] + E16t [N x M] + col partial sums (aux)
template<int MODE>
__global__ void __launch_bounds__(512, 2)
gemm256(const f16* __restrict__ A, const f16* __restrict__ Bm, float* __restrict__ Cf,
        f16* __restrict__ E16, f16* __restrict__ E16t,
        int K, long sA, long sB, float scale, float* __restrict__ aux) {
  __shared__ f16 sb[65536];  // 128 KB: A0[16384] B0[16384] A1[16384] B1[16384]
  const int t = threadIdx.x, l = t & 63, w = t >> 6;
  const int wr = w >> 2, wc = w & 3;
  const int bid = blockIdx.x;
  const int swzb = (bid & 7) * 64 + (bid >> 3);  // XCD-chunked (512 % 8 == 0)
  const long b = swzb >> 6;
  const int inner = swzb & 63;
  const int bx = inner >> 2, by = inner & 3;  // by fastest: 4 consecutive blocks share B-panel in L2
  const char* Abyte = (const char*)(A + b * sA + (long)(by * 256) * K);
  const char* Bbyte = (const char*)(Bm + b * sB + (long)(bx * 256) * K);

  int offSrc[4];
#pragma unroll
  for (int i = 0; i < 4; ++i) {
    int cid = i * 512 + t, row = cid >> 3, slot = cid & 7;
    offSrc[i] = row * (K * 2) + ((slot ^ (row & 7)) << 4);
  }
  int offAf[8][2], offBf[4][2];
#pragma unroll
  for (int mi = 0; mi < 8; ++mi) {
    int r = wr * 128 + mi * 16 + (l & 15);
#pragma unroll
    for (int ks = 0; ks < 2; ++ks)
      offAf[mi][ks] = r * 64 + ((((ks << 2) + (l >> 4)) ^ (r & 7)) << 3);
  }
#pragma unroll
  for (int ni = 0; ni < 4; ++ni) {
    int r = wc * 64 + ni * 16 + (l & 15);
#pragma unroll
    for (int ks = 0; ks < 2; ++ks)
      offBf[ni][ks] = r * 64 + ((((ks << 2) + (l >> 4)) ^ (r & 7)) << 3);
  }

  const int NT = K >> 6;
  f32x4 acc[8][4] = {};

  auto STAGE = [&](int kt, int bsel) {
    f16* la = sb + bsel * 32768;
    f16* lb = la + 16384;
    const char* as = Abyte + (long)kt * 128;
    const char* bs = Bbyte + (long)kt * 128;
#pragma unroll
    for (int i = 0; i < 4; ++i)
      gload16(as + offSrc[i], la + (i * 512 + (w << 6)) * 8);
#pragma unroll
    for (int i = 0; i < 4; ++i)
      gload16(bs + offSrc[i], lb + (i * 512 + (w << 6)) * 8);
  };

  STAGE(0, 0);
  for (int kt = 0; kt < NT; ++kt) {
    const int cur = kt & 1;
    if (kt + 1 < NT) {
      STAGE(kt + 1, cur ^ 1);
      asm volatile("s_waitcnt vmcnt(8)" ::: "memory");
    } else {
      asm volatile("s_waitcnt vmcnt(0)" ::: "memory");
    }
    __builtin_amdgcn_s_barrier();
    asm volatile("" ::: "memory");
    const f16* la = sb + cur * 32768;
    const f16* lb = la + 16384;
#pragma unroll
    for (int ks = 0; ks < 2; ++ks) {
      f16x8 bf[4];
#pragma unroll
      for (int ni = 0; ni < 4; ++ni) bf[ni] = *(const f16x8*)(lb + offBf[ni][ks]);
#pragma unroll
      for (int mi = 0; mi < 8; ++mi) {
        f16x8 af = *(const f16x8*)(la + offAf[mi][ks]);
#pragma unroll
        for (int ni = 0; ni < 4; ++ni)
          acc[mi][ni] = __builtin_amdgcn_mfma_f32_16x16x32_f16(af, bf[ni], acc[mi][ni], 0, 0, 0);
      }
    }
    asm volatile("s_waitcnt lgkmcnt(0)" ::: "memory");
    __builtin_amdgcn_s_barrier();
    asm volatile("" ::: "memory");
  }

  const int i0 = by * 256, j0 = bx * 256;
  if (MODE == 2) {
    float csum[4] = {};
#pragma unroll
    for (int mi = 0; mi < 8; ++mi)
#pragma unroll
      for (int ni = 0; ni < 4; ++ni)
#pragma unroll
        for (int q = 0; q < 4; ++q) {
          float e = __expf(acc[mi][ni][q] * scale);
          acc[mi][ni][q] = e;
          csum[ni] += e;
        }
#pragma unroll
    for (int ni = 0; ni < 4; ++ni) {
      csum[ni] += __shfl_xor(csum[ni], 16);
      csum[ni] += __shfl_xor(csum[ni], 32);
    }
    float* colp = (float*)(sb + 34816);
    if (l < 16) {
#pragma unroll
      for (int ni = 0; ni < 4; ++ni) colp[wr * 256 + wc * 64 + ni * 16 + l] = csum[ni];
    }
    __syncthreads();
    if (t < 256) aux[(b * 4 + by) * 4096 + bx * 256 + t] = colp[t] + colp[256 + t];
    f16* E16b = E16 + b * 4194304L;
    f16* E16tb = E16t + b * 4194304L;
#pragma unroll
    for (int s = 0; s < 4; ++s) {
      if (wr == (s >> 1)) {
        const int h = s & 1;
#pragma unroll
        for (int m2 = 0; m2 < 4; ++m2)
#pragma unroll
          for (int ni = 0; ni < 4; ++ni)
#pragma unroll
            for (int q = 0; q < 4; ++q)
              sb[(m2 * 16 + (l >> 4) * 4 + q) * 264 + wc * 64 + ni * 16 + (l & 15)] =
                  (f16)acc[h * 4 + m2][ni][q];
      }
      __syncthreads();
#pragma unroll
      for (int ii = 0; ii < 4; ++ii) {
        int cid = ii * 512 + t, r = cid >> 5, cc = cid & 31;
        *(f16x8*)(E16b + (long)(i0 + s * 64 + r) * 4096 + j0 + cc * 8) =
            *(const f16x8*)(sb + r * 264 + cc * 8);
      }
      const int q4 = w >> 1, r8 = l >> 3, ic = l & 7;
#pragma unroll
      for (int ii = 0; ii < 4; ++ii) {
        int j = q4 * 64 + r8 * 8 + (w & 1) * 4 + ii;
        f16x8 v;
#pragma unroll
        for (int k2 = 0; k2 < 8; ++k2) v[k2] = sb[(ic * 8 + k2) * 264 + j];
        *(f16x8*)(E16tb + (long)(j0 + j) * 1024 + i0 + s * 64 + ic * 8) = v;
      }
      __syncthreads();
    }
  }
}

// ================= fused: split-K gram (160) + MODE3 (512) = 672 blocks, 512 thr, 136 KB ======
// bids 0..159: gram half-K block. bid = (pairIdx*2 + h)*8 + b; pair (by<=bx) of 256-panels;
//   computes partial mid (256x256 f32) over global kts [32h, 32h+32) -> midS scratch.
//   Fused Hf writer: A-tile if bx-by==1 (slot0) or bx-by==2 (slot1); B-tile if bx-by==3 (slot0)
//   or (bx-by==1 && by>=1) (slot1). Each (panel, 1024-col window) covered exactly once.
// bids 160..671: out = (Q * E^T) * inv[col]  (256^2 tile, K=1024) — verified gemm256<3> body
__global__ void __launch_bounds__(512, 2)
fused3(const f16* __restrict__ Q, const f16* __restrict__ Et, float* __restrict__ Cf,
       const float* __restrict__ invg,
       const f16* __restrict__ E, const f16* __restrict__ inv2sg,
       float* __restrict__ Hf, float* __restrict__ midS) {
  __shared__ f16 sb[69632];  // 136 KB (gram uses all; MODE3 uses first 128 KB)
  const int t = threadIdx.x, l = t & 63, w = t >> 6;
  const int wr = w >> 2, wc = w & 3;

  if (blockIdx.x < 160) {  // ---------------- gram half-K path
    const int bid = blockIdx.x;
    const long b = bid & 7;            // batch = XCD
    const int rest = bid >> 3;         // 0..19
    const int h = rest & 1;            // K-half
    int by = 0, r = rest >> 1;         // triangular 0..9 -> (by, bx), bx >= by
    while (r >= 4 - by) { r -= 4 - by; ++by; }
    const int bx = by + r;
    const char* Abyte = (const char*)(E + b * 4194304L + (long)(by * 256) * 4096 + 2048L * h);
    const char* Bbyte = (const char*)(E + b * 4194304L + (long)(bx * 256) * 4096 + 2048L * h);
    const int d = bx - by;
    const int wA = (d == 1) ? 0 : (d == 2 ? 1 : -1);
    const int wB = (d == 3) ? 0 : ((d == 1 && by >= 1) ? 1 : -1);
    f16* invl = sb + 65536;
    gload16((const char*)(inv2sg + b * 4096) + (long)t * 16, invl + (w << 6) * 8);
    int offSrc[4];
#pragma unroll
    for (int i = 0; i < 4; ++i) {
      int cid = i * 512 + t, row = cid >> 3, slot = cid & 7;
      offSrc[i] = row * 8192 + ((slot ^ (row & 7)) << 4);
    }
    int offAf[8][2], offBf[4][2];
#pragma unroll
    for (int mi = 0; mi < 8; ++mi) {
      int rr = wr * 128 + mi * 16 + (l & 15);
#pragma unroll
      for (int ks = 0; ks < 2; ++ks)
        offAf[mi][ks] = rr * 64 + ((((ks << 2) + (l >> 4)) ^ (rr & 7)) << 3);
    }
#pragma unroll
    for (int ni = 0; ni < 4; ++ni) {
      int rr = wc * 64 + ni * 16 + (l & 15);
#pragma unroll
      for (int ks = 0; ks < 2; ++ks)
        offBf[ni][ks] = rr * 64 + ((((ks << 2) + (l >> 4)) ^ (rr & 7)) << 3);
    }
    f32x4 acc[8][4] = {};
    auto STAGE = [&](int lk, int bsel) {
      f16* la = sb + bsel * 32768;
      f16* lb = la + 16384;
      const char* as = Abyte + (long)lk * 128;
      const char* bs = Bbyte + (long)lk * 128;
#pragma unroll
      for (int i = 0; i < 4; ++i) gload16(as + offSrc[i], la + (i * 512 + (w << 6)) * 8);
#pragma unroll
      for (int i = 0; i < 4; ++i) gload16(bs + offSrc[i], lb + (i * 512 + (w << 6)) * 8);
    };
    STAGE(0, 0);
    for (int lk = 0; lk < 32; ++lk) {
      const int cur = lk & 1;
      if (lk + 1 < 32) {
        STAGE(lk + 1, cur ^ 1);
        const int ps = (lk - 1) >> 4;
        const bool wrote = (lk >= 1) && (wA == ps || wB == ps);
        if (wrote) asm volatile("s_waitcnt vmcnt(40)" ::: "memory");
        else       asm volatile("s_waitcnt vmcnt(8)" ::: "memory");
      } else {
        asm volatile("s_waitcnt vmcnt(0)" ::: "memory");
      }
      __builtin_amdgcn_s_barrier();
      asm volatile("" ::: "memory");
      const int ktg = 32 * h + lk;  // global K-tile index (64 cols each)
      const f16* la = sb + cur * 32768;
      const f16* lb = la + 16384;
#pragma unroll
      for (int ks = 0; ks < 2; ++ks) {
        const f16x8 invv = *(const f16x8*)(invl + ktg * 64 + ks * 32 + ((l >> 4) << 3));
        f16x8 bf[4];
#pragma unroll
        for (int ni = 0; ni < 4; ++ni) bf[ni] = *(const f16x8*)(lb + offBf[ni][ks]);
#pragma unroll
        for (int mi = 0; mi < 8; ++mi) {
          f16x8 af = *(const f16x8*)(la + offAf[mi][ks]) * invv;  // A-side only: inv^2*4096
#pragma unroll
          for (int ni = 0; ni < 4; ++ni)
            acc[mi][ni] = __builtin_amdgcn_mfma_f32_16x16x32_f16(af, bf[ni], acc[mi][ni], 0, 0, 0);
        }
      }
      const int slot = lk >> 4;
      if (wA == slot || wB == slot) {  // fused Hf writer (at most one per iteration)
        const int panel = (wA == slot) ? by : bx;
        const f16* src = (wA == slot) ? la : lb;
        const float iv = sqrtf((float)invl[ktg * 64 + l]) * (1.0f / 64.0f);  // inv = sqrt(inv2s)/64
        float* hp = Hf + b * 4194304L + (long)(panel * 256 + w * 32) * 4096 + ktg * 64 + l;
#pragma unroll
        for (int rr2 = 0; rr2 < 32; ++rr2) {
          const int row = w * 32 + rr2;  // 8 waves x 32 rows
          f16 ev = src[row * 64 + ((((l >> 3) ^ (row & 7)) << 3) | (l & 7))];
          hp[(long)rr2 * 4096] = (float)ev * iv;
        }
      }
      asm volatile("s_waitcnt lgkmcnt(0)" ::: "memory");
      __builtin_amdgcn_s_barrier();
      asm volatile("" ::: "memory");
    }
    // store partial mid tile (f32) to scratch
    float* mt = midS + (long)(((rest >> 1) * 8 + b) * 2 + h) * 65536;
#pragma unroll
    for (int mi = 0; mi < 8; ++mi)
#pragma unroll
      for (int ni = 0; ni < 4; ++ni)
#pragma unroll
        for (int q = 0; q < 4; ++q)
          mt[(wr * 128 + mi * 16 + (l >> 4) * 4 + q) * 256 + wc * 64 + ni * 16 + (l & 15)] =
              acc[mi][ni][q];
  } else {  // ---------------- MODE3 path (verified gemm256<3> body, K=1024)
    const int bid = blockIdx.x - 160;
    const int swzb = (bid & 7) * 64 + (bid >> 3);
    const long b = swzb >> 6;
    const int inner = swzb & 63;
    const int bx = inner >> 2, by = inner & 3;
    const char* Abyte = (const char*)(Q + b * 1048576L + (long)(by * 256) * 1024);
    const char* Bbyte = (const char*)(Et + b * 4194304L + (long)(bx * 256) * 1024);
    int offSrc[4];
#pragma unroll
    for (int i = 0; i < 4; ++i) {
      int cid = i * 512 + t, row = cid >> 3, slot = cid & 7;
      offSrc[i] = row * 2048 + ((slot ^ (row & 7)) << 4);
    }
    int offAf[8][2], offBf[4][2];
#pragma unroll
    for (int mi = 0; mi < 8; ++mi) {
      int r = wr * 128 + mi * 16 + (l & 15);
#pragma unroll
      for (int ks = 0; ks < 2; ++ks)
        offAf[mi][ks] = r * 64 + ((((ks << 2) + (l >> 4)) ^ (r & 7)) << 3);
    }
#pragma unroll
    for (int ni = 0; ni < 4; ++ni) {
      int r = wc * 64 + ni * 16 + (l & 15);
#pragma unroll
      for (int ks = 0; ks < 2; ++ks)
        offBf[ni][ks] = r * 64 + ((((ks << 2) + (l >> 4)) ^ (r & 7)) << 3);
    }
    f32x4 acc[8][4] = {};
    auto STAGE = [&](int kt, int bsel) {
      f16* la = sb + bsel * 32768;
      f16* lb = la + 16384;
      const char* as = Abyte + (long)kt * 128;
      const char* bs = Bbyte + (long)kt * 128;
#pragma unroll
      for (int i = 0; i < 4; ++i) gload16(as + offSrc[i], la + (i * 512 + (w << 6)) * 8);
#pragma unroll
      for (int i = 0; i < 4; ++i) gload16(bs + offSrc[i], lb + (i * 512 + (w << 6)) * 8);
    };
    STAGE(0, 0);
    for (int kt = 0; kt < 16; ++kt) {
      const int cur = kt & 1;
      if (kt + 1 < 16) {
        STAGE(kt + 1, cur ^ 1);
        asm volatile("s_waitcnt vmcnt(8)" ::: "memory");
      } else {
        asm volatile("s_waitcnt vmcnt(0)" ::: "memory");
      }
      __builtin_amdgcn_s_barrier();
      asm volatile("" ::: "memory");
      const f16* la = sb + cur * 32768;
      const f16* lb = la + 16384;
#pragma unroll
      for (int ks = 0; ks < 2; ++ks) {
        f16x8 bf[4];
#pragma unroll
        for (int ni = 0; ni < 4; ++ni) bf[ni] = *(const f16x8*)(lb + offBf[ni][ks]);
#pragma unroll
        for (int mi = 0; mi < 8; ++mi) {
          f16x8 af = *(const f16x8*)(la + offAf[mi][ks]);
#pragma unroll
          for (int ni = 0; ni < 4; ++ni)
            acc[mi][ni] = __builtin_amdgcn_mfma_f32_16x16x32_f16(af, bf[ni], acc[mi][ni], 0, 0, 0);
        }
      }
      asm volatile("s_waitcnt lgkmcnt(0)" ::: "memory");
      __builtin_amdgcn_s_barrier();
      asm volatile("" ::: "memory");
    }
    const float* ip = invg + b * 4096 + bx * 256 + wc * 64;
    float iv[4];
#pragma unroll
    for (int ni = 0; ni < 4; ++ni) iv[ni] = ip[ni * 16 + (l & 15)];
    float* Cb = Cf + b * 4194304L + (long)(by * 256 + wr * 128) * 4096 + bx * 256 + wc * 64;
#pragma unroll
    for (int mi = 0; mi < 8; ++mi)
#pragma unroll
      for (int ni = 0; ni < 4; ++ni)
#pragma unroll
        for (int q = 0; q < 4; ++q)
          Cb[(long)(mi * 16 + (l >> 4) * 4 + q) * 4096 + ni * 16 + (l & 15)] = acc[mi][ni][q] * iv[ni];
  }
}

// ================= gram reduce: sum K-halves, subtract I, square, partial loss ================
// grid (80, 8): x = pairIdx*8 + b (tile), y = chunk of 8192 elems; 256 threads
__global__ void __launch_bounds__(256)
gram_red(const float* __restrict__ midS, float* __restrict__ parts) {
  const int tile = blockIdx.x, ck = blockIdx.y, t = threadIdx.x;
  int by = 0, r = tile >> 3;  // pairIdx -> (by, bx)
  while (r >= 4 - by) { r -= 4 - by; ++by; }
  const int bx = by + r;
  const bool diag = (by == bx);
  const float* m0 = midS + (long)(tile * 2) * 65536 + ck * 8192;
  const float* m1 = m0 + 65536;
  float p = 0.f;
  for (int i = t; i < 8192; i += 256) {
    int gi = ck * 8192 + i;
    float e = (m0[i] + m1[i]) * (1.0f / 4096.0f);
    if (diag && (gi >> 8) == (gi & 255)) e -= 1.f;
    p += e * e;
  }
  if (!diag) p *= 2.f;
#pragma unroll
  for (int d2 = 32; d2; d2 >>= 1) p += __shfl_down(p, d2);
  __shared__ float red[4];
  if ((t & 63) == 0) red[t >> 6] = p;
  __syncthreads();
  if (t == 0) parts[tile * 8 + ck] = red[0] + red[1] + red[2] + red[3];
}

// ================= fused Q+K projection: one pass over Xk =====================================
__global__ void __launch_bounds__(512)
proj_qk(const float* __restrict__ X, const f16* __restrict__ Wq16, const f16* __restrict__ Wk16,
        const float* __restrict__ bq, const float* __restrict__ bk,
        f16* __restrict__ Q, f16* __restrict__ Kt) {
  __shared__ f16 sb[20480];  // Wq[8192] Wk[8192] Xt[4096]
  f16* Wqs = sb;
  f16* Wks = sb + 8192;
  f16* Xs = sb + 16384;
  const int t = threadIdx.x, l = t & 63, w = t >> 6;
  const int wrq = w >> 1, wcq = w & 1;
  const int bg = blockIdx.z, g = bg & 3;
  const long b = bg >> 2;
  const int p0 = blockIdx.x * 128;
  const float* Xb = X + b * 1048576 + (long)g * 262144;
  const char* WqB = (const char*)(Wq16 + g * 65536);
  const char* WkB = (const char*)(Wk16 + g * 65536);
  int wOff[2];
#pragma unroll
  for (int i = 0; i < 2; ++i) {
    int c = i * 512 + t, row = c >> 2, slot = (c & 3) ^ ((row >> 1) & 3);
    wOff[i] = row * 512 + (slot << 4);
  }
  const int xp = t & 127, xc = t >> 7;
  const float* xS = Xb + (long)(xc * 8) * 1024 + p0 + xp;
  const int xo = swz(xp, xc);
  int offW[4], offX[4];
#pragma unroll
  for (int i = 0; i < 4; ++i) {
    int rc = wrq * 64 + i * 16 + (l & 15);
    offW[i] = swz(rc, l >> 4);
    int rp = wcq * 64 + i * 16 + (l & 15);
    offX[i] = swz(rp, l >> 4);
  }
  f32x4 accq[4][4] = {}, acck[4][4] = {};
  for (int k0 = 0; k0 < 256; k0 += 32) {
#pragma unroll
    for (int i = 0; i < 2; ++i) {
      gload16(WqB + wOff[i] + k0 * 2, Wqs + (i * 512 + (w << 6)) * 8);
      gload16(WkB + wOff[i] + k0 * 2, Wks + (i * 512 + (w << 6)) * 8);
    }
    const float* xs = xS + (long)k0 * 1024;
    f16x8 v;
#pragma unroll
    for (int d = 0; d < 8; ++d) v[d] = (f16)xs[(long)d * 1024];
    *(f16x8*)((char*)Xs + xo) = v;
    __syncthreads();
    f16x8 qf[4], kf[4], xf[4];
#pragma unroll
    for (int i = 0; i < 4; ++i) {
      qf[i] = *(const f16x8*)((const char*)Wqs + offW[i]);
      kf[i] = *(const f16x8*)((const char*)Wks + offW[i]);
      xf[i] = *(const f16x8*)((const char*)Xs + offX[i]);
    }
#pragma unroll
    for (int mi = 0; mi < 4; ++mi)
#pragma unroll
      for (int ni = 0; ni < 4; ++ni) {
        accq[mi][ni] = __builtin_amdgcn_mfma_f32_16x16x32_f16(qf[mi], xf[ni], accq[mi][ni], 0, 0, 0);
        acck[ni][mi] = __builtin_amdgcn_mfma_f32_16x16x32_f16(xf[ni], kf[mi], acck[ni][mi], 0, 0, 0);
      }
    __syncthreads();
  }
  f16* Qb = Q + b * 1048576 + (long)(g * 256 + wrq * 64) * 1024 + p0 + wcq * 64;
#pragma unroll
  for (int mi = 0; mi < 4; ++mi)
#pragma unroll
    for (int q = 0; q < 4; ++q) {
      float bv = bq[g * 256 + wrq * 64 + mi * 16 + (l >> 4) * 4 + q];
#pragma unroll
      for (int ni = 0; ni < 4; ++ni)
        Qb[(long)(mi * 16 + (l >> 4) * 4 + q) * 1024 + ni * 16 + (l & 15)] = (f16)(accq[mi][ni][q] + bv);
    }
  f16* Kb = Kt + b * 1048576 + (long)(p0 + wcq * 64) * 1024 + g * 256 + wrq * 64;
  float bcol[4];
#pragma unroll
  for (int ni = 0; ni < 4; ++ni) bcol[ni] = bk[g * 256 + wrq * 64 + ni * 16 + (l & 15)];
#pragma unroll
  for (int mi = 0; mi < 4; ++mi)
#pragma unroll
    for (int q = 0; q < 4; ++q)
#pragma unroll
      for (int ni = 0; ni < 4; ++ni)
        Kb[(long)(mi * 16 + (l >> 4) * 4 + q) * 1024 + ni * 16 + (l & 15)] = (f16)(acck[mi][ni][q] + bcol[ni]);
}

// ================= V projection: full-group tile, one pass over Xq ============================
__global__ void __launch_bounds__(512)
proj_v(const float* __restrict__ X, const f16* __restrict__ Wv16, const float* __restrict__ bv,
       f16* __restrict__ Vt) {
  __shared__ f16 sb[12288];
  f16* Wvs = sb;
  f16* Xs = sb + 8192;
  const int t = threadIdx.x, l = t & 63, w = t >> 6;
  const int wrq = w >> 1, wcq = w & 1;
  const int bg = blockIdx.z, g = bg & 3;
  const long b = bg >> 2;
  const int p0 = blockIdx.x * 128;
  const float* Xb = X + b * 4194304 + (long)g * 1048576;
  const char* WvB = (const char*)(Wv16 + g * 65536);
  int wOff[2];
#pragma unroll
  for (int i = 0; i < 2; ++i) {
    int c = i * 512 + t, row = c >> 2, slot = (c & 3) ^ ((row >> 1) & 3);
    wOff[i] = row * 512 + (slot << 4);
  }
  const int xp = t & 127, xc = t >> 7;
  const float* xS = Xb + (long)(xc * 8) * 4096 + p0 + xp;
  const int xo = swz(xp, xc);
  int offW[4], offX[4];
#pragma unroll
  for (int i = 0; i < 4; ++i) {
    int rc = wrq * 64 + i * 16 + (l & 15);
    offW[i] = swz(rc, l >> 4);
    int rp = wcq * 64 + i * 16 + (l & 15);
    offX[i] = swz(rp, l >> 4);
  }
  f32x4 acc[4][4] = {};
  for (int k0 = 0; k0 < 256; k0 += 32) {
#pragma unroll
    for (int i = 0; i < 2; ++i)
      gload16(WvB + wOff[i] + k0 * 2, Wvs + (i * 512 + (w << 6)) * 8);
    const float* xs = xS + (long)k0 * 4096;
    f16x8 v;
#pragma unroll
    for (int d = 0; d < 8; ++d) v[d] = (f16)xs[(long)d * 4096];
    *(f16x8*)((char*)Xs + xo) = v;
    __syncthreads();
    f16x8 wf[4], xf[4];
#pragma unroll
    for (int i = 0; i < 4; ++i) {
      wf[i] = *(const f16x8*)((const char*)Wvs + offW[i]);
      xf[i] = *(const f16x8*)((const char*)Xs + offX[i]);
    }
#pragma unroll
    for (int mi = 0; mi < 4; ++mi)
#pragma unroll
      for (int ni = 0; ni < 4; ++ni)
        acc[mi][ni] = __builtin_amdgcn_mfma_f32_16x16x32_f16(xf[mi], wf[ni], acc[mi][ni], 0, 0, 0);
    __syncthreads();
  }
  f16* Vb = Vt + b * 4194304 + (long)(p0 + wcq * 64) * 1024 + g * 256 + wrq * 64;
  float bcol[4];
#pragma unroll
  for (int ni = 0; ni < 4; ++ni) bcol[ni] = bv[g * 256 + wrq * 64 + ni * 16 + (l & 15)];
#pragma unroll
  for (int mi = 0; mi < 4; ++mi)
#pragma unroll
    for (int q = 0; q < 4; ++q)
#pragma unroll
      for (int ni = 0; ni < 4; ++ni)
        Vb[(long)(mi * 16 + (l >> 4) * 4 + q) * 1024 + ni * 16 + (l & 15)] = (f16)(acc[mi][ni][q] + bcol[ni]);
}

// ---------------- inv[b][j] = 1/colsum;  inv2s = inv^2*4096 (f16, for gram A-side scaling)
__global__ void __launch_bounds__(256)
inv_k(const float* __restrict__ colsum, float* __restrict__ inv, f16* __restrict__ inv2s) {
  int gid = blockIdx.x * 256 + threadIdx.x;  // 8*4096
  int b = gid >> 12, j = gid & 4095;
  const float* cp = colsum + (long)(b * 4) * 4096 + j;
  float s = 0.f;
#pragma unroll
  for (int my = 0; my < 4; ++my) s += cp[my * 4096];
  float iv = 1.f / s;
  inv[gid] = iv;
  inv2s[gid] = (f16)(iv * iv * 4096.0f);
}

// ---------------- one fused f32->f16 weight convert (3 tensors of 262144)
__global__ void cvt3(const float* __restrict__ a, const float* __restrict__ b2,
                     const float* __restrict__ c, f16* __restrict__ da,
                     f16* __restrict__ db, f16* __restrict__ dc) {
  int i = blockIdx.x * 256 + threadIdx.x;
  int which = i >> 18, r = i & 262143;
  if (which == 0) da[r] = (f16)a[r];
  else if (which == 1) db[r] = (f16)b2[r];
  else dc[r] = (f16)c[r];
}

__global__ void __launch_bounds__(256)
finalize_k(const float* __restrict__ parts, float* __restrict__ o) {
  const int t = threadIdx.x;
  float s = 0.f;
  for (int i = t; i < 640; i += 256) s += parts[i];
#pragma unroll
  for (int d = 32; d; d >>= 1) s += __shfl_down(s, d);
  __shared__ float red[4];
  if ((t & 63) == 0) red[t >> 6] = s;
  __syncthreads();
  if (t == 0) *o = (red[0] + red[1] + red[2] + red[3]) * (1.0f / 8388608.0f);
}

extern "C" void kernel_launch(void* const* d_in, const int* in_sizes, int n_in,
                              void* d_out, int out_size, void* d_ws, size_t ws_size,
                              hipStream_t stream) {
  const float* Xq = (const float*)d_in[0];
  const float* Xk = (const float*)d_in[1];
  const float* Wq = (const float*)d_in[2];
  const float* bq = (const float*)d_in[3];
  const float* Wk = (const float*)d_in[4];
  const float* bk = (const float*)d_in[5];
  const float* Wv = (const float*)d_in[6];
  const float* bv = (const float*)d_in[7];
  float* out = (float*)d_out;
  float* loss_out = out + 33554432;
  float* Hf = out + 33554433;  // H f32 output [8][1024][4096]

  char* ws = (char*)d_ws;
  f16* W16q = (f16*)(ws);
  f16* W16k = (f16*)(ws + (1 << 19));
  f16* W16v = (f16*)(ws + 2L * (1 << 19));
  f16* Q16  = (f16*)(ws + 3L * (1 << 19));                                  // [8][1024][1024]
  f16* Kt16 = (f16*)(ws + 3L * (1 << 19) + (1L << 24));                     // [8][1024][1024]
  f16* Vt16 = (f16*)(ws + 3L * (1 << 19) + 2L * (1 << 24));                 // [8][4096][1024]
  f16* E16  = (f16*)(ws + 3L * (1 << 19) + 2L * (1 << 24) + (1L << 26));    // [8][1024][4096]
  f16* E16t = (f16*)(ws + 3L * (1 << 19) + 2L * (1 << 24) + 2L * (1 << 26));// [8][4096][1024]
  char* tail = ws + 3L * (1 << 19) + 2L * (1 << 24) + 3L * (1 << 26);
  float* parts = (float*)tail;                         // 640 f32
  float* invb  = (float*)(tail + 8192);                // [8][4096] f32
  f16*   inv2s = (f16*)(tail + 8192 + 131072);         // [8][4096] f16
  float* midS  = (float*)(tail + 8192 + 131072 + 65536); // 160 x 64K f32 = 40 MB
  // colsum [8][4][4096] f32 = 512KB, overlaps W16q (dead after projections)
  float* colsum = (float*)(ws);

  cvt3<<<3072, 256, 0, stream>>>(Wq, Wk, Wv, W16q, W16k, W16v);

  // Q [C x Pk] natural + K transposed [Pk x C] in one pass over Xk; V transposed [Pq x C]
  proj_qk<<<dim3(8, 1, 32), 512, 0, stream>>>(Xk, W16q, W16k, bq, bk, Q16, Kt16);
  proj_v <<<dim3(32, 1, 32), 512, 0, stream>>>(Xq, W16v, bv, Vt16);

  // E = exp(K^T V /32) -> E16 + E16t (f16) + column partial sums (256^2 tile, counted vmcnt)
  gemm256<2><<<512, 512, 0, stream>>>(Kt16, Vt16, nullptr, E16, E16t,
      1024, 1L << 20, 1L << 22, 0.03125f, colsum);

  inv_k<<<128, 256, 0, stream>>>(colsum, invb, inv2s);

  // fused: split-K gram (160 blocks, partial mid -> scratch) + out = Q*E^T*inv (512 blocks)
  fused3<<<672, 512, 0, stream>>>(Q16, E16t, out, invb, E16, inv2s, Hf, midS);

  // sum K-halves, subtract I, square, reduce
  gram_red<<<dim3(80, 8), 256, 0, stream>>>(midS, parts);
  finalize_k<<<1, 256, 0, stream>>>(parts, loss_out);
}

// Round 20
// 362.992 us; speedup vs baseline: 1.4096x; 1.0216x over previous
//
#include <hip/hip_runtime.h>

typedef _Float16 f16;
typedef f16 f16x4 __attribute__((ext_vector_type(4)));
typedef f16 f16x8 __attribute__((ext_vector_type(8)));
typedef float f32x4 __attribute__((ext_vector_type(4)));

// async global->LDS, 16B per lane; lds ptr must be wave-uniform base (HW adds lane*16)
__device__ __forceinline__ void gload16(const void* g, void* ldsbase) {
  __builtin_amdgcn_global_load_lds((const __attribute__((address_space(1))) unsigned int*)g,
                                   (__attribute__((address_space(3))) unsigned int*)ldsbase, 16, 0, 0);
}

// swizzled byte offset of 16B chunk c (k-chunk) of row `row` in a [rows][32] f16 tile (BK=32 kernels)
__device__ __forceinline__ int swz(int row, int c) {
  return row * 64 + ((c ^ ((row >> 1) & 3)) << 4);
}

// ================= 256x256 tile, BK=64, 512 threads, counted-vmcnt schedule =================
// MODE 2: E = exp(A*B^T * scale) -> E16 [M x N] + E16t [N x M] + col partial sums (aux)
template<int MODE>
__global__ void __launch_bounds__(512, 2)
gemm256(const f16* __restrict__ A, const f16* __restrict__ Bm, float* __restrict__ Cf,
        f16* __restrict__ E16, f16* __restrict__ E16t,
        int K, long sA, long sB, float scale, float* __restrict__ aux) {
  __shared__ f16 sb[65536];  // 128 KB: A0[16384] B0[16384] A1[16384] B1[16384]
  const int t = threadIdx.x, l = t & 63, w = t >> 6;
  const int wr = w >> 2, wc = w & 3;
  const int bid = blockIdx.x;
  const int swzb = (bid & 7) * 64 + (bid >> 3);  // XCD-chunked (512 % 8 == 0)
  const long b = swzb >> 6;
  const int inner = swzb & 63;
  const int bx = inner >> 2, by = inner & 3;  // by fastest: 4 consecutive blocks share B-panel in L2
  const char* Abyte = (const char*)(A + b * sA + (long)(by * 256) * K);
  const char* Bbyte = (const char*)(Bm + b * sB + (long)(bx * 256) * K);

  int offSrc[4];
#pragma unroll
  for (int i = 0; i < 4; ++i) {
    int cid = i * 512 + t, row = cid >> 3, slot = cid & 7;
    offSrc[i] = row * (K * 2) + ((slot ^ (row & 7)) << 4);
  }
  int offAf[8][2], offBf[4][2];
#pragma unroll
  for (int mi = 0; mi < 8; ++mi) {
    int r = wr * 128 + mi * 16 + (l & 15);
#pragma unroll
    for (int ks = 0; ks < 2; ++ks)
      offAf[mi][ks] = r * 64 + ((((ks << 2) + (l >> 4)) ^ (r & 7)) << 3);
  }
#pragma unroll
  for (int ni = 0; ni < 4; ++ni) {
    int r = wc * 64 + ni * 16 + (l & 15);
#pragma unroll
    for (int ks = 0; ks < 2; ++ks)
      offBf[ni][ks] = r * 64 + ((((ks << 2) + (l >> 4)) ^ (r & 7)) << 3);
  }

  const int NT = K >> 6;
  f32x4 acc[8][4] = {};

  auto STAGE = [&](int kt, int bsel) {
    f16* la = sb + bsel * 32768;
    f16* lb = la + 16384;
    const char* as = Abyte + (long)kt * 128;
    const char* bs = Bbyte + (long)kt * 128;
#pragma unroll
    for (int i = 0; i < 4; ++i)
      gload16(as + offSrc[i], la + (i * 512 + (w << 6)) * 8);
#pragma unroll
    for (int i = 0; i < 4; ++i)
      gload16(bs + offSrc[i], lb + (i * 512 + (w << 6)) * 8);
  };

  STAGE(0, 0);
  for (int kt = 0; kt < NT; ++kt) {
    const int cur = kt & 1;
    if (kt + 1 < NT) {
      STAGE(kt + 1, cur ^ 1);
      asm volatile("s_waitcnt vmcnt(8)" ::: "memory");
    } else {
      asm volatile("s_waitcnt vmcnt(0)" ::: "memory");
    }
    __builtin_amdgcn_s_barrier();
    asm volatile("" ::: "memory");
    const f16* la = sb + cur * 32768;
    const f16* lb = la + 16384;
#pragma unroll
    for (int ks = 0; ks < 2; ++ks) {
      f16x8 bf[4];
#pragma unroll
      for (int ni = 0; ni < 4; ++ni) bf[ni] = *(const f16x8*)(lb + offBf[ni][ks]);
#pragma unroll
      for (int mi = 0; mi < 8; ++mi) {
        f16x8 af = *(const f16x8*)(la + offAf[mi][ks]);
#pragma unroll
        for (int ni = 0; ni < 4; ++ni)
          acc[mi][ni] = __builtin_amdgcn_mfma_f32_16x16x32_f16(af, bf[ni], acc[mi][ni], 0, 0, 0);
      }
    }
    asm volatile("s_waitcnt lgkmcnt(0)" ::: "memory");
    __builtin_amdgcn_s_barrier();
    asm volatile("" ::: "memory");
  }

  const int i0 = by * 256, j0 = bx * 256;
  if (MODE == 2) {
    float csum[4] = {};
#pragma unroll
    for (int mi = 0; mi < 8; ++mi)
#pragma unroll
      for (int ni = 0; ni < 4; ++ni)
#pragma unroll
        for (int q = 0; q < 4; ++q) {
          float e = __expf(acc[mi][ni][q] * scale);
          acc[mi][ni][q] = e;
          csum[ni] += e;
        }
#pragma unroll
    for (int ni = 0; ni < 4; ++ni) {
      csum[ni] += __shfl_xor(csum[ni], 16);
      csum[ni] += __shfl_xor(csum[ni], 32);
    }
    float* colp = (float*)(sb + 34816);
    if (l < 16) {
#pragma unroll
      for (int ni = 0; ni < 4; ++ni) colp[wr * 256 + wc * 64 + ni * 16 + l] = csum[ni];
    }
    __syncthreads();
    if (t < 256) aux[(b * 4 + by) * 4096 + bx * 256 + t] = colp[t] + colp[256 + t];
    f16* E16b = E16 + b * 4194304L;
    f16* E16tb = E16t + b * 4194304L;
#pragma unroll
    for (int s = 0; s < 4; ++s) {
      if (wr == (s >> 1)) {
        const int h = s & 1;
#pragma unroll
        for (int m2 = 0; m2 < 4; ++m2)
#pragma unroll
          for (int ni = 0; ni < 4; ++ni)
#pragma unroll
            for (int q = 0; q < 4; ++q)
              sb[(m2 * 16 + (l >> 4) * 4 + q) * 264 + wc * 64 + ni * 16 + (l & 15)] =
                  (f16)acc[h * 4 + m2][ni][q];
      }
      __syncthreads();
#pragma unroll
      for (int ii = 0; ii < 4; ++ii) {
        int cid = ii * 512 + t, r = cid >> 5, cc = cid & 31;
        *(f16x8*)(E16b + (long)(i0 + s * 64 + r) * 4096 + j0 + cc * 8) =
            *(const f16x8*)(sb + r * 264 + cc * 8);
      }
      const int q4 = w >> 1, r8 = l >> 3, ic = l & 7;
#pragma unroll
      for (int ii = 0; ii < 4; ++ii) {
        int j = q4 * 64 + r8 * 8 + (w & 1) * 4 + ii;
        f16x8 v;
#pragma unroll
        for (int k2 = 0; k2 < 8; ++k2) v[k2] = sb[(ic * 8 + k2) * 264 + j];
        *(f16x8*)(E16tb + (long)(j0 + j) * 1024 + i0 + s * 64 + ic * 8) = v;
      }
      __syncthreads();
    }
  }
}

// ================= fused: split-K gram (160) + MODE3 (512) = 672 blocks, 512 thr, 136 KB ======
// bids 0..159: gram half-K block. bid = (pairIdx*2 + h)*8 + b; pair (by<=bx) of 256-panels;
//   computes partial mid (256x256 f32) over global kts [32h, 32h+32) -> midS scratch.
//   Fused Hf writer: A-tile if bx-by==1 (slot0) or bx-by==2 (slot1); B-tile if bx-by==3 (slot0)
//   or (bx-by==1 && by>=1) (slot1). Each (panel, 1024-col window) covered exactly once.
// bids 160..671: out = (Q * E^T) * inv[col]  (256^2 tile, K=1024) — verified gemm256<3> body
__global__ void __launch_bounds__(512, 2)
fused3(const f16* __restrict__ Q, const f16* __restrict__ Et, float* __restrict__ Cf,
       const float* __restrict__ invg,
       const f16* __restrict__ E, const f16* __restrict__ inv2sg,
       float* __restrict__ Hf, float* __restrict__ midS) {
  __shared__ f16 sb[69632];  // 136 KB (gram uses all; MODE3 uses first 128 KB)
  const int t = threadIdx.x, l = t & 63, w = t >> 6;
  const int wr = w >> 2, wc = w & 3;

  if (blockIdx.x < 160) {  // ---------------- gram half-K path
    const int bid = blockIdx.x;
    const long b = bid & 7;            // batch = XCD
    const int rest = bid >> 3;         // 0..19
    const int h = rest & 1;            // K-half
    int by = 0, r = rest >> 1;         // triangular 0..9 -> (by, bx), bx >= by
    while (r >= 4 - by) { r -= 4 - by; ++by; }
    const int bx = by + r;
    const char* Abyte = (const char*)(E + b * 4194304L + (long)(by * 256) * 4096 + 2048L * h);
    const char* Bbyte = (const char*)(E + b * 4194304L + (long)(bx * 256) * 4096 + 2048L * h);
    const int d = bx - by;
    const int wA = (d == 1) ? 0 : (d == 2 ? 1 : -1);
    const int wB = (d == 3) ? 0 : ((d == 1 && by >= 1) ? 1 : -1);
    f16* invl = sb + 65536;
    gload16((const char*)(inv2sg + b * 4096) + (long)t * 16, invl + (w << 6) * 8);
    int offSrc[4];
#pragma unroll
    for (int i = 0; i < 4; ++i) {
      int cid = i * 512 + t, row = cid >> 3, slot = cid & 7;
      offSrc[i] = row * 8192 + ((slot ^ (row & 7)) << 4);
    }
    int offAf[8][2], offBf[4][2];
#pragma unroll
    for (int mi = 0; mi < 8; ++mi) {
      int rr = wr * 128 + mi * 16 + (l & 15);
#pragma unroll
      for (int ks = 0; ks < 2; ++ks)
        offAf[mi][ks] = rr * 64 + ((((ks << 2) + (l >> 4)) ^ (rr & 7)) << 3);
    }
#pragma unroll
    for (int ni = 0; ni < 4; ++ni) {
      int rr = wc * 64 + ni * 16 + (l & 15);
#pragma unroll
      for (int ks = 0; ks < 2; ++ks)
        offBf[ni][ks] = rr * 64 + ((((ks << 2) + (l >> 4)) ^ (rr & 7)) << 3);
    }
    f32x4 acc[8][4] = {};
    auto STAGE = [&](int lk, int bsel) {
      f16* la = sb + bsel * 32768;
      f16* lb = la + 16384;
      const char* as = Abyte + (long)lk * 128;
      const char* bs = Bbyte + (long)lk * 128;
#pragma unroll
      for (int i = 0; i < 4; ++i) gload16(as + offSrc[i], la + (i * 512 + (w << 6)) * 8);
#pragma unroll
      for (int i = 0; i < 4; ++i) gload16(bs + offSrc[i], lb + (i * 512 + (w << 6)) * 8);
    };
    STAGE(0, 0);
    for (int lk = 0; lk < 32; ++lk) {
      const int cur = lk & 1;
      if (lk + 1 < 32) {
        STAGE(lk + 1, cur ^ 1);
        const int ps = (lk - 1) >> 4;
        const bool wrote = (lk >= 1) && (wA == ps || wB == ps);
        if (wrote) asm volatile("s_waitcnt vmcnt(40)" ::: "memory");
        else       asm volatile("s_waitcnt vmcnt(8)" ::: "memory");
      } else {
        asm volatile("s_waitcnt vmcnt(0)" ::: "memory");
      }
      __builtin_amdgcn_s_barrier();
      asm volatile("" ::: "memory");
      const int ktg = 32 * h + lk;  // global K-tile index (64 cols each)
      const f16* la = sb + cur * 32768;
      const f16* lb = la + 16384;
#pragma unroll
      for (int ks = 0; ks < 2; ++ks) {
        const f16x8 invv = *(const f16x8*)(invl + ktg * 64 + ks * 32 + ((l >> 4) << 3));
        f16x8 bf[4];
#pragma unroll
        for (int ni = 0; ni < 4; ++ni) bf[ni] = *(const f16x8*)(lb + offBf[ni][ks]);
#pragma unroll
        for (int mi = 0; mi < 8; ++mi) {
          f16x8 af = *(const f16x8*)(la + offAf[mi][ks]) * invv;  // A-side only: inv^2*4096
#pragma unroll
          for (int ni = 0; ni < 4; ++ni)
            acc[mi][ni] = __builtin_amdgcn_mfma_f32_16x16x32_f16(af, bf[ni], acc[mi][ni], 0, 0, 0);
        }
      }
      const int slot = lk >> 4;
      if (wA == slot || wB == slot) {  // fused Hf writer (at most one per iteration)
        const int panel = (wA == slot) ? by : bx;
        const f16* src = (wA == slot) ? la : lb;
        const float iv = sqrtf((float)invl[ktg * 64 + l]) * (1.0f / 64.0f);  // inv = sqrt(inv2s)/64
        float* hp = Hf + b * 4194304L + (long)(panel * 256 + w * 32) * 4096 + ktg * 64 + l;
#pragma unroll
        for (int rr2 = 0; rr2 < 32; ++rr2) {
          const int row = w * 32 + rr2;  // 8 waves x 32 rows
          f16 ev = src[row * 64 + ((((l >> 3) ^ (row & 7)) << 3) | (l & 7))];
          hp[(long)rr2 * 4096] = (float)ev * iv;
        }
      }
      asm volatile("s_waitcnt lgkmcnt(0)" ::: "memory");
      __builtin_amdgcn_s_barrier();
      asm volatile("" ::: "memory");
    }
    // store partial mid tile (f32) to scratch
    float* mt = midS + (long)(((rest >> 1) * 8 + b) * 2 + h) * 65536;
#pragma unroll
    for (int mi = 0; mi < 8; ++mi)
#pragma unroll
      for (int ni = 0; ni < 4; ++ni)
#pragma unroll
        for (int q = 0; q < 4; ++q)
          mt[(wr * 128 + mi * 16 + (l >> 4) * 4 + q) * 256 + wc * 64 + ni * 16 + (l & 15)] =
              acc[mi][ni][q];
  } else {  // ---------------- MODE3 path (verified gemm256<3> body, K=1024)
    const int bid = blockIdx.x - 160;
    const int swzb = (bid & 7) * 64 + (bid >> 3);
    const long b = swzb >> 6;
    const int inner = swzb & 63;
    const int bx = inner >> 2, by = inner & 3;
    const char* Abyte = (const char*)(Q + b * 1048576L + (long)(by * 256) * 1024);
    const char* Bbyte = (const char*)(Et + b * 4194304L + (long)(bx * 256) * 1024);
    int offSrc[4];
#pragma unroll
    for (int i = 0; i < 4; ++i) {
      int cid = i * 512 + t, row = cid >> 3, slot = cid & 7;
      offSrc[i] = row * 2048 + ((slot ^ (row & 7)) << 4);
    }
    int offAf[8][2], offBf[4][2];
#pragma unroll
    for (int mi = 0; mi < 8; ++mi) {
      int r = wr * 128 + mi * 16 + (l & 15);
#pragma unroll
      for (int ks = 0; ks < 2; ++ks)
        offAf[mi][ks] = r * 64 + ((((ks << 2) + (l >> 4)) ^ (r & 7)) << 3);
    }
#pragma unroll
    for (int ni = 0; ni < 4; ++ni) {
      int r = wc * 64 + ni * 16 + (l & 15);
#pragma unroll
      for (int ks = 0; ks < 2; ++ks)
        offBf[ni][ks] = r * 64 + ((((ks << 2) + (l >> 4)) ^ (r & 7)) << 3);
    }
    f32x4 acc[8][4] = {};
    auto STAGE = [&](int kt, int bsel) {
      f16* la = sb + bsel * 32768;
      f16* lb = la + 16384;
      const char* as = Abyte + (long)kt * 128;
      const char* bs = Bbyte + (long)kt * 128;
#pragma unroll
      for (int i = 0; i < 4; ++i) gload16(as + offSrc[i], la + (i * 512 + (w << 6)) * 8);
#pragma unroll
      for (int i = 0; i < 4; ++i) gload16(bs + offSrc[i], lb + (i * 512 + (w << 6)) * 8);
    };
    STAGE(0, 0);
    for (int kt = 0; kt < 16; ++kt) {
      const int cur = kt & 1;
      if (kt + 1 < 16) {
        STAGE(kt + 1, cur ^ 1);
        asm volatile("s_waitcnt vmcnt(8)" ::: "memory");
      } else {
        asm volatile("s_waitcnt vmcnt(0)" ::: "memory");
      }
      __builtin_amdgcn_s_barrier();
      asm volatile("" ::: "memory");
      const f16* la = sb + cur * 32768;
      const f16* lb = la + 16384;
#pragma unroll
      for (int ks = 0; ks < 2; ++ks) {
        f16x8 bf[4];
#pragma unroll
        for (int ni = 0; ni < 4; ++ni) bf[ni] = *(const f16x8*)(lb + offBf[ni][ks]);
#pragma unroll
        for (int mi = 0; mi < 8; ++mi) {
          f16x8 af = *(const f16x8*)(la + offAf[mi][ks]);
#pragma unroll
          for (int ni = 0; ni < 4; ++ni)
            acc[mi][ni] = __builtin_amdgcn_mfma_f32_16x16x32_f16(af, bf[ni], acc[mi][ni], 0, 0, 0);
        }
      }
      asm volatile("s_waitcnt lgkmcnt(0)" ::: "memory");
      __builtin_amdgcn_s_barrier();
      asm volatile("" ::: "memory");
    }
    const float* ip = invg + b * 4096 + bx * 256 + wc * 64;
    float iv[4];
#pragma unroll
    for (int ni = 0; ni < 4; ++ni) iv[ni] = ip[ni * 16 + (l & 15)];
    float* Cb = Cf + b * 4194304L + (long)(by * 256 + wr * 128) * 4096 + bx * 256 + wc * 64;
#pragma unroll
    for (int mi = 0; mi < 8; ++mi)
#pragma unroll
      for (int ni = 0; ni < 4; ++ni)
#pragma unroll
        for (int q = 0; q < 4; ++q)
          Cb[(long)(mi * 16 + (l >> 4) * 4 + q) * 4096 + ni * 16 + (l & 15)] = acc[mi][ni][q] * iv[ni];
  }
}

// ================= gram reduce: sum K-halves, subtract I, square, partial loss ================
// grid (80, 8): x = pairIdx*8 + b (tile), y = chunk of 8192 elems; 256 threads, f32x4 loads
__global__ void __launch_bounds__(256)
gram_red(const float* __restrict__ midS, float* __restrict__ parts) {
  const int tile = blockIdx.x, ck = blockIdx.y, t = threadIdx.x;
  int by = 0, r = tile >> 3;  // pairIdx -> (by, bx)
  while (r >= 4 - by) { r -= 4 - by; ++by; }
  const int bx = by + r;
  const bool diag = (by == bx);
  const float* m0 = midS + (long)(tile * 2) * 65536 + ck * 8192;
  const float* m1 = m0 + 65536;
  float p = 0.f;
  for (int v = t; v < 2048; v += 256) {  // 2048 f32x4 = 8192 elems
    f32x4 a = *(const f32x4*)(m0 + v * 4);
    f32x4 c = *(const f32x4*)(m1 + v * 4);
#pragma unroll
    for (int e2 = 0; e2 < 4; ++e2) {
      int gi = ck * 8192 + v * 4 + e2;
      float e = (a[e2] + c[e2]) * (1.0f / 4096.0f);
      if (diag && (gi >> 8) == (gi & 255)) e -= 1.f;
      p += e * e;
    }
  }
  if (!diag) p *= 2.f;
#pragma unroll
  for (int d2 = 32; d2; d2 >>= 1) p += __shfl_down(p, d2);
  __shared__ float red[4];
  if ((t & 63) == 0) red[t >> 6] = p;
  __syncthreads();
  if (t == 0) parts[tile * 8 + ck] = red[0] + red[1] + red[2] + red[3];
}

// ================= fused Q+K projection: one pass over Xk =====================================
__global__ void __launch_bounds__(512)
proj_qk(const float* __restrict__ X, const f16* __restrict__ Wq16, const f16* __restrict__ Wk16,
        const float* __restrict__ bq, const float* __restrict__ bk,
        f16* __restrict__ Q, f16* __restrict__ Kt) {
  __shared__ f16 sb[20480];  // Wq[8192] Wk[8192] Xt[4096]
  f16* Wqs = sb;
  f16* Wks = sb + 8192;
  f16* Xs = sb + 16384;
  const int t = threadIdx.x, l = t & 63, w = t >> 6;
  const int wrq = w >> 1, wcq = w & 1;
  const int bg = blockIdx.z, g = bg & 3;
  const long b = bg >> 2;
  const int p0 = blockIdx.x * 128;
  const float* Xb = X + b * 1048576 + (long)g * 262144;
  const char* WqB = (const char*)(Wq16 + g * 65536);
  const char* WkB = (const char*)(Wk16 + g * 65536);
  int wOff[2];
#pragma unroll
  for (int i = 0; i < 2; ++i) {
    int c = i * 512 + t, row = c >> 2, slot = (c & 3) ^ ((row >> 1) & 3);
    wOff[i] = row * 512 + (slot << 4);
  }
  const int xp = t & 127, xc = t >> 7;
  const float* xS = Xb + (long)(xc * 8) * 1024 + p0 + xp;
  const int xo = swz(xp, xc);
  int offW[4], offX[4];
#pragma unroll
  for (int i = 0; i < 4; ++i) {
    int rc = wrq * 64 + i * 16 + (l & 15);
    offW[i] = swz(rc, l >> 4);
    int rp = wcq * 64 + i * 16 + (l & 15);
    offX[i] = swz(rp, l >> 4);
  }
  f32x4 accq[4][4] = {}, acck[4][4] = {};
  for (int k0 = 0; k0 < 256; k0 += 32) {
#pragma unroll
    for (int i = 0; i < 2; ++i) {
      gload16(WqB + wOff[i] + k0 * 2, Wqs + (i * 512 + (w << 6)) * 8);
      gload16(WkB + wOff[i] + k0 * 2, Wks + (i * 512 + (w << 6)) * 8);
    }
    const float* xs = xS + (long)k0 * 1024;
    f16x8 v;
#pragma unroll
    for (int d = 0; d < 8; ++d) v[d] = (f16)xs[(long)d * 1024];
    *(f16x8*)((char*)Xs + xo) = v;
    __syncthreads();
    f16x8 qf[4], kf[4], xf[4];
#pragma unroll
    for (int i = 0; i < 4; ++i) {
      qf[i] = *(const f16x8*)((const char*)Wqs + offW[i]);
      kf[i] = *(const f16x8*)((const char*)Wks + offW[i]);
      xf[i] = *(const f16x8*)((const char*)Xs + offX[i]);
    }
#pragma unroll
    for (int mi = 0; mi < 4; ++mi)
#pragma unroll
      for (int ni = 0; ni < 4; ++ni) {
        accq[mi][ni] = __builtin_amdgcn_mfma_f32_16x16x32_f16(qf[mi], xf[ni], accq[mi][ni], 0, 0, 0);
        acck[ni][mi] = __builtin_amdgcn_mfma_f32_16x16x32_f16(xf[ni], kf[mi], acck[ni][mi], 0, 0, 0);
      }
    __syncthreads();
  }
  f16* Qb = Q + b * 1048576 + (long)(g * 256 + wrq * 64) * 1024 + p0 + wcq * 64;
#pragma unroll
  for (int mi = 0; mi < 4; ++mi)
#pragma unroll
    for (int q = 0; q < 4; ++q) {
      float bv = bq[g * 256 + wrq * 64 + mi * 16 + (l >> 4) * 4 + q];
#pragma unroll
      for (int ni = 0; ni < 4; ++ni)
        Qb[(long)(mi * 16 + (l >> 4) * 4 + q) * 1024 + ni * 16 + (l & 15)] = (f16)(accq[mi][ni][q] + bv);
    }
  f16* Kb = Kt + b * 1048576 + (long)(p0 + wcq * 64) * 1024 + g * 256 + wrq * 64;
  float bcol[4];
#pragma unroll
  for (int ni = 0; ni < 4; ++ni) bcol[ni] = bk[g * 256 + wrq * 64 + ni * 16 + (l & 15)];
#pragma unroll
  for (int mi = 0; mi < 4; ++mi)
#pragma unroll
    for (int q = 0; q < 4; ++q)
#pragma unroll
      for (int ni = 0; ni < 4; ++ni)
        Kb[(long)(mi * 16 + (l >> 4) * 4 + q) * 1024 + ni * 16 + (l & 15)] = (f16)(acck[mi][ni][q] + bcol[ni]);
}

// ================= V projection: full-group tile, one pass over Xq ============================
__global__ void __launch_bounds__(512)
proj_v(const float* __restrict__ X, const f16* __restrict__ Wv16, const float* __restrict__ bv,
       f16* __restrict__ Vt) {
  __shared__ f16 sb[12288];
  f16* Wvs = sb;
  f16* Xs = sb + 8192;
  const int t = threadIdx.x, l = t & 63, w = t >> 6;
  const int wrq = w >> 1, wcq = w & 1;
  const int bg = blockIdx.z, g = bg & 3;
  const long b = bg >> 2;
  const int p0 = blockIdx.x * 128;
  const float* Xb = X + b * 4194304 + (long)g * 1048576;
  const char* WvB = (const char*)(Wv16 + g * 65536);
  int wOff[2];
#pragma unroll
  for (int i = 0; i < 2; ++i) {
    int c = i * 512 + t, row = c >> 2, slot = (c & 3) ^ ((row >> 1) & 3);
    wOff[i] = row * 512 + (slot << 4);
  }
  const int xp = t & 127, xc = t >> 7;
  const float* xS = Xb + (long)(xc * 8) * 4096 + p0 + xp;
  const int xo = swz(xp, xc);
  int offW[4], offX[4];
#pragma unroll
  for (int i = 0; i < 4; ++i) {
    int rc = wrq * 64 + i * 16 + (l & 15);
    offW[i] = swz(rc, l >> 4);
    int rp = wcq * 64 + i * 16 + (l & 15);
    offX[i] = swz(rp, l >> 4);
  }
  f32x4 acc[4][4] = {};
  for (int k0 = 0; k0 < 256; k0 += 32) {
#pragma unroll
    for (int i = 0; i < 2; ++i)
      gload16(WvB + wOff[i] + k0 * 2, Wvs + (i * 512 + (w << 6)) * 8);
    const float* xs = xS + (long)k0 * 4096;
    f16x8 v;
#pragma unroll
    for (int d = 0; d < 8; ++d) v[d] = (f16)xs[(long)d * 4096];
    *(f16x8*)((char*)Xs + xo) = v;
    __syncthreads();
    f16x8 wf[4], xf[4];
#pragma unroll
    for (int i = 0; i < 4; ++i) {
      wf[i] = *(const f16x8*)((const char*)Wvs + offW[i]);
      xf[i] = *(const f16x8*)((const char*)Xs + offX[i]);
    }
#pragma unroll
    for (int mi = 0; mi < 4; ++mi)
#pragma unroll
      for (int ni = 0; ni < 4; ++ni)
        acc[mi][ni] = __builtin_amdgcn_mfma_f32_16x16x32_f16(xf[mi], wf[ni], acc[mi][ni], 0, 0, 0);
    __syncthreads();
  }
  f16* Vb = Vt + b * 4194304 + (long)(p0 + wcq * 64) * 1024 + g * 256 + wrq * 64;
  float bcol[4];
#pragma unroll
  for (int ni = 0; ni < 4; ++ni) bcol[ni] = bv[g * 256 + wrq * 64 + ni * 16 + (l & 15)];
#pragma unroll
  for (int mi = 0; mi < 4; ++mi)
#pragma unroll
    for (int q = 0; q < 4; ++q)
#pragma unroll
      for (int ni = 0; ni < 4; ++ni)
        Vb[(long)(mi * 16 + (l >> 4) * 4 + q) * 1024 + ni * 16 + (l & 15)] = (f16)(acc[mi][ni][q] + bcol[ni]);
}

// ---------------- inv[b][j] = 1/colsum;  inv2s = inv^2*4096 (f16, for gram A-side scaling)
__global__ void __launch_bounds__(256)
inv_k(const float* __restrict__ colsum, float* __restrict__ inv, f16* __restrict__ inv2s) {
  int gid = blockIdx.x * 256 + threadIdx.x;  // 8*4096
  int b = gid >> 12, j = gid & 4095;
  const float* cp = colsum + (long)(b * 4) * 4096 + j;
  float s = 0.f;
#pragma unroll
  for (int my = 0; my < 4; ++my) s += cp[my * 4096];
  float iv = 1.f / s;
  inv[gid] = iv;
  inv2s[gid] = (f16)(iv * iv * 4096.0f);
}

// ---------------- one fused f32->f16 weight convert (3 tensors of 262144)
__global__ void cvt3(const float* __restrict__ a, const float* __restrict__ b2,
                     const float* __restrict__ c, f16* __restrict__ da,
                     f16* __restrict__ db, f16* __restrict__ dc) {
  int i = blockIdx.x * 256 + threadIdx.x;
  int which = i >> 18, r = i & 262143;
  if (which == 0) da[r] = (f16)a[r];
  else if (which == 1) db[r] = (f16)b2[r];
  else dc[r] = (f16)c[r];
}

__global__ void __launch_bounds__(256)
finalize_k(const float* __restrict__ parts, float* __restrict__ o) {
  const int t = threadIdx.x;
  float s = 0.f;
  for (int i = t; i < 640; i += 256) s += parts[i];
#pragma unroll
  for (int d = 32; d; d >>= 1) s += __shfl_down(s, d);
  __shared__ float red[4];
  if ((t & 63) == 0) red[t >> 6] = s;
  __syncthreads();
  if (t == 0) *o = (red[0] + red[1] + red[2] + red[3]) * (1.0f / 8388608.0f);
}

extern "C" void kernel_launch(void* const* d_in, const int* in_sizes, int n_in,
                              void* d_out, int out_size, void* d_ws, size_t ws_size,
                              hipStream_t stream) {
  const float* Xq = (const float*)d_in[0];
  const float* Xk = (const float*)d_in[1];
  const float* Wq = (const float*)d_in[2];
  const float* bq = (const float*)d_in[3];
  const float* Wk = (const float*)d_in[4];
  const float* bk = (const float*)d_in[5];
  const float* Wv = (const float*)d_in[6];
  const float* bv = (const float*)d_in[7];
  float* out = (float*)d_out;
  float* loss_out = out + 33554432;
  float* Hf = out + 33554433;  // H f32 output [8][1024][4096]

  char* ws = (char*)d_ws;
  f16* W16q = (f16*)(ws);
  f16* W16k = (f16*)(ws + (1 << 19));
  f16* W16v = (f16*)(ws + 2L * (1 << 19));
  f16* Q16  = (f16*)(ws + 3L * (1 << 19));                                  // [8][1024][1024]
  f16* Kt16 = (f16*)(ws + 3L * (1 << 19) + (1L << 24));                     // [8][1024][1024]
  f16* Vt16 = (f16*)(ws + 3L * (1 << 19) + 2L * (1 << 24));                 // [8][4096][1024]
  f16* E16  = (f16*)(ws + 3L * (1 << 19) + 2L * (1 << 24) + (1L << 26));    // [8][1024][4096]
  f16* E16t = (f16*)(ws + 3L * (1 << 19) + 2L * (1 << 24) + 2L * (1 << 26));// [8][4096][1024]
  char* tail = ws + 3L * (1 << 19) + 2L * (1 << 24) + 3L * (1 << 26);
  float* parts = (float*)tail;                         // 640 f32
  float* invb  = (float*)(tail + 8192);                // [8][4096] f32
  f16*   inv2s = (f16*)(tail + 8192 + 131072);         // [8][4096] f16
  float* midS  = (float*)(tail + 8192 + 131072 + 65536); // 160 x 64K f32 = 40 MB
  // colsum [8][4][4096] f32 = 512KB, overlaps W16q (dead after projections)
  float* colsum = (float*)(ws);

  cvt3<<<3072, 256, 0, stream>>>(Wq, Wk, Wv, W16q, W16k, W16v);

  // Q [C x Pk] natural + K transposed [Pk x C] in one pass over Xk; V transposed [Pq x C]
  proj_qk<<<dim3(8, 1, 32), 512, 0, stream>>>(Xk, W16q, W16k, bq, bk, Q16, Kt16);
  proj_v <<<dim3(32, 1, 32), 512, 0, stream>>>(Xq, W16v, bv, Vt16);

  // E = exp(K^T V /32) -> E16 + E16t (f16) + column partial sums (256^2 tile, counted vmcnt)
  gemm256<2><<<512, 512, 0, stream>>>(Kt16, Vt16, nullptr, E16, E16t,
      1024, 1L << 20, 1L << 22, 0.03125f, colsum);

  inv_k<<<128, 256, 0, stream>>>(colsum, invb, inv2s);

  // fused: split-K gram (160 blocks, partial mid -> scratch) + out = Q*E^T*inv (512 blocks)
  fused3<<<672, 512, 0, stream>>>(Q16, E16t, out, invb, E16, inv2s, Hf, midS);

  // sum K-halves, subtract I, square, reduce (f32x4 vectorized)
  gram_red<<<dim3(80, 8), 256, 0, stream>>>(midS, parts);
  finalize_k<<<1, 256, 0, stream>>>(parts, loss_out);
}